// Round 1
// baseline (422.684 us; speedup 1.0000x reference)
//
#include <hip/hip_runtime.h>

// ShiftedWindowMSA fused kernel for MI355X (gfx950).
// Grid: 2048 blocks = (b, u, v) windows; 512 threads = 8 waves; 1 wave = 1 head in attention.
// ws: wTperm bf16[768][256] (w1 transposed + column-permuted to (t,head,e) order), bperm f32[768].

typedef short bf16x8 __attribute__((ext_vector_type(8)));   // 8 bf16 in 4 VGPRs (guide-verified for MFMA builtins)
typedef float f32x4 __attribute__((ext_vector_type(4)));
typedef unsigned short u16;
typedef u16 u16x8 __attribute__((ext_vector_type(8)));
typedef u16 u16x4 __attribute__((ext_vector_type(4)));

#define MFMA16 __builtin_amdgcn_mfma_f32_16x16x32_bf16

__device__ __forceinline__ u16 f2bf(float f) {          // RNE fp32 -> bf16
  union { float f; unsigned int u; } c; c.f = f;
  unsigned int uu = c.u;
  return (u16)((uu + 0x7fffu + ((uu >> 16) & 1u)) >> 16);
}

// ---- LDS layout (bytes) ----
// sA  [64 rows][256 ch] bf16, 16B-chunk XOR swizzle (chunk ^= row&7)      @ 0      (32 KB) -- aliased by sP after GEMM
// sQ  same layout                                                        @ 32768  (32 KB)
// sK  same layout                                                        @ 65536  (32 KB)
// sVt [256 ch][64 key] bf16, chunk ^= ch&7                               @ 98304  (32 KB)
// sPos f32[169]                                                          @ 131072
// sP per-wave [64 q][32 key] bf16, chunk ^= row&3, wave*4096 over sA
#define OFF_A   0
#define OFF_Q   32768
#define OFF_K   65536
#define OFF_VT  98304
#define OFF_POS 131072
#define SMEM_BYTES (131072 + 704)

__global__ void prep_w(const float* __restrict__ w1, const float* __restrict__ b1,
                       u16* __restrict__ wT, float* __restrict__ bp) {
  int g = blockIdx.x * 256 + threadIdx.x;        // [0, 768*64)
  int np = g >> 6;                               // permuted column n' = t*256 + hh*32 + eidx
  int kq = (g & 63) << 2;                        // k base (4 per thread)
  int t  = np >> 8;
  int cc = np & 255;
  int hh = cc >> 5, ei = cc & 31;
  int n  = (ei * 8 + hh) * 3 + t;                // original w1 column: c = eidx*8+hh, col = c*3+t
  u16x4 o;
  o.x = f2bf(w1[(kq + 0) * 768 + n]);
  o.y = f2bf(w1[(kq + 1) * 768 + n]);
  o.z = f2bf(w1[(kq + 2) * 768 + n]);
  o.w = f2bf(w1[(kq + 3) * 768 + n]);
  *(u16x4*)(wT + np * 256 + kq) = o;
  if (g < 768) {
    int t2 = g >> 8, cc2 = g & 255;
    int n2 = ((cc2 & 31) * 8 + (cc2 >> 5)) * 3 + t2;
    bp[g] = b1[n2];
  }
}

__launch_bounds__(512, 2)
__global__ void swin_fused(const float* __restrict__ x, const u16* __restrict__ wT,
                           const float* __restrict__ bp, const float* __restrict__ pos,
                           float* __restrict__ out) {
  __shared__ __align__(16) char smem[SMEM_BYTES];
  const int tid  = threadIdx.x;
  const int wave = tid >> 6;
  const int lane = tid & 63;
  const int quad = lane >> 4;
  const int l16  = lane & 15;
  const int blk  = blockIdx.x;
  const int b = blk >> 6, u = (blk >> 3) & 7, v = blk & 7;

  float* sPos = (float*)(smem + OFF_POS);
  if (tid < 169) sPos[tid] = pos[tid];

  // ---------- phase 1: stage x window -> sA (bf16) ----------
  // roll(qkv, -4): window row h' reads x at (h'+4)%56 (note: -7//2 == -4 in Python!)
  {
    const int xbase = b * (56 * 56 * 256);
#pragma unroll
    for (int it = 0; it < 4; ++it) {
      int idx = tid + it * 512;                  // 64 rows * 32 chunks(8ch)
      int row = idx >> 5;
      int ck  = idx & 31;
      char* dst = smem + OFF_A + row * 512 + ((ck ^ (row & 7)) << 4);
      u16x8 val{};
      if (row < 49) {
        int i = row / 7, j = row % 7;
        int sh = u * 7 + i + 4; if (sh >= 56) sh -= 56;
        int sw = v * 7 + j + 4; if (sw >= 56) sw -= 56;
        const float4* src = (const float4*)(x + xbase + (sh * 56 + sw) * 256 + ck * 8);
        float4 f0 = src[0];
        float4 f1 = src[1];
        val.s0 = f2bf(f0.x); val.s1 = f2bf(f0.y); val.s2 = f2bf(f0.z); val.s3 = f2bf(f0.w);
        val.s4 = f2bf(f1.x); val.s5 = f2bf(f1.y); val.s6 = f2bf(f1.z); val.s7 = f2bf(f1.w);
      }
      *(u16x8*)dst = val;                        // rows 49..63 zeroed (keeps pads finite)
    }
  }
  __syncthreads();

  // ---------- phase 2: QKV GEMM: [64x256] @ [256x768] ----------
  // wave w owns 6 n-tiles (96 permuted cols); B-frags straight from global (L2-resident wT)
  {
    f32x4 acc[4][6];
#pragma unroll
    for (int m = 0; m < 4; ++m)
#pragma unroll
      for (int i = 0; i < 6; ++i) acc[m][i] = (f32x4){0.f, 0.f, 0.f, 0.f};

    const int nt0 = wave * 6;
    const u16* gB[6];
#pragma unroll
    for (int i = 0; i < 6; ++i)
      gB[i] = wT + ((nt0 + i) * 16 + l16) * 256 + quad * 8;
    const char* aRow[4];
    int aSw[4];
#pragma unroll
    for (int m = 0; m < 4; ++m) {
      int row = m * 16 + l16;
      aRow[m] = smem + OFF_A + row * 512;
      aSw[m]  = row & 7;
    }

    bf16x8 bcur[6], bnxt[6], acur[4], anxt[4];
#pragma unroll
    for (int i = 0; i < 6; ++i) bcur[i] = *(const bf16x8*)(gB[i]);
#pragma unroll
    for (int m = 0; m < 4; ++m) acur[m] = *(const bf16x8*)(aRow[m] + ((quad ^ aSw[m]) << 4));

#pragma unroll
    for (int ks = 0; ks < 8; ++ks) {
      if (ks < 7) {                               // register double-buffer prefetch
        const int k1 = ks + 1;
#pragma unroll
        for (int i = 0; i < 6; ++i) bnxt[i] = *(const bf16x8*)(gB[i] + k1 * 32);
#pragma unroll
        for (int m = 0; m < 4; ++m)
          anxt[m] = *(const bf16x8*)(aRow[m] + (((k1 * 4 + quad) ^ aSw[m]) << 4));
      }
#pragma unroll
      for (int m = 0; m < 4; ++m)
#pragma unroll
        for (int i = 0; i < 6; ++i)
          acc[m][i] = MFMA16(acur[m], bcur[i], acc[m][i], 0, 0, 0);
      if (ks < 7) {
#pragma unroll
        for (int i = 0; i < 6; ++i) bcur[i] = bnxt[i];
#pragma unroll
        for (int m = 0; m < 4; ++m) acur[m] = anxt[m];
      }
    }

    // epilogue: +bias, scatter to sQ / sK / sVt(transposed)
#pragma unroll
    for (int i = 0; i < 6; ++i) {
      const int np   = (nt0 + i) * 16 + l16;
      const float bi = bp[np];
      const int t  = np >> 8;                     // uniform per tile (tiles are 16-aligned, t bound at 256)
      const int cc = np & 255;                    // head*32 + eidx
      if (t < 2) {
        char* buf = smem + (t == 0 ? OFF_Q : OFF_K);
        const int ccc = ((cc >> 3)), cb2 = (cc & 7) << 1;
#pragma unroll
        for (int m = 0; m < 4; ++m)
#pragma unroll
          for (int r = 0; r < 4; ++r) {
            int row = m * 16 + quad * 4 + r;
            *(u16*)(buf + row * 512 + (((ccc ^ (row & 7)) << 4) | cb2)) = f2bf(acc[m][i][r] + bi);
          }
      } else {
        char* buf = smem + OFF_VT + cc * 128;
        const int csw = cc & 7;
#pragma unroll
        for (int m = 0; m < 4; ++m)
#pragma unroll
          for (int r = 0; r < 4; ++r) {
            int row = m * 16 + quad * 4 + r;      // key index
            *(u16*)(buf + ((((row >> 3) ^ csw) << 4) | ((row & 7) << 1))) = f2bf(acc[m][i][r] + bi);
          }
      }
    }
  }
  __syncthreads();

  // ---------- phase 3: attention, wave = head ----------
  {
    const int hh = wave;
    const int cb = hh * 32;

    bf16x8 qf[4], kf[4];
#pragma unroll
    for (int m = 0; m < 4; ++m) {
      int row = m * 16 + l16;
      int off = row * 512 + (((hh * 4 + quad) ^ (row & 7)) << 4);
      qf[m] = *(const bf16x8*)(smem + OFF_Q + off);
      kf[m] = *(const bf16x8*)(smem + OFF_K + off);
    }
    f32x4 s[4][4];
#pragma unroll
    for (int m = 0; m < 4; ++m)
#pragma unroll
      for (int n = 0; n < 4; ++n) s[m][n] = (f32x4){0.f, 0.f, 0.f, 0.f};
#pragma unroll
    for (int m = 0; m < 4; ++m)
#pragma unroll
      for (int n = 0; n < 4; ++n)
        s[m][n] = MFMA16(qf[m], kf[n], s[m][n], 0, 0, 0);   // S[q][k] = Q.K^T

    // scale + rel-pos bias + shift masks + softmax (in C-layout registers)
    const bool rowm = (u == 7), colm = (v == 7);
    int ki[4], kj[4]; bool kok[4], kro[4], kco[4];
#pragma unroll
    for (int n = 0; n < 4; ++n) {
      int k = n * 16 + l16;
      ki[n] = k / 7; kj[n] = k % 7;
      kok[n] = (k < 49);
      kro[n] = (ki[n] >= 4);
      kco[n] = (kj[n] >= 4);
    }
    const float scale = 0.17677669529663687f;    // 1/sqrt(32)
    float rsum[4][4];
#pragma unroll
    for (int m = 0; m < 4; ++m) {
#pragma unroll
      for (int r = 0; r < 4; ++r) {
        int q = m * 16 + quad * 4 + r;
        int qi = q / 7, qj = q % 7;
        bool qro = (qi >= 4), qco = (qj >= 4);
        float vmax = -3e30f;
#pragma unroll
        for (int n = 0; n < 4; ++n) {
          bool bad = (!kok[n]) || (rowm && (qro != kro[n])) || (colm && (qco != kco[n]));
          float sv = bad ? -1e30f
                         : s[m][n][r] * scale + sPos[(ki[n] - qi + 6) * 13 + (kj[n] - qj + 6)];
          s[m][n][r] = sv;
          vmax = fmaxf(vmax, sv);
        }
        vmax = fmaxf(vmax, __shfl_xor(vmax, 1));
        vmax = fmaxf(vmax, __shfl_xor(vmax, 2));
        vmax = fmaxf(vmax, __shfl_xor(vmax, 4));
        vmax = fmaxf(vmax, __shfl_xor(vmax, 8));
        float sum = 0.f;
#pragma unroll
        for (int n = 0; n < 4; ++n) {
          float p = __expf(s[m][n][r] - vmax);   // masked/pad keys -> exp(-1e30-m) = 0
          s[m][n][r] = p;
          sum += p;
        }
        sum += __shfl_xor(sum, 1);
        sum += __shfl_xor(sum, 2);
        sum += __shfl_xor(sum, 4);
        sum += __shfl_xor(sum, 8);
        rsum[m][r] = sum;
      }
    }

    // PV in two key-halves through per-wave sP (aliases dead sA region)
    char* sP = smem + OFF_A + wave * 4096;
    f32x4 o[4][2];
#pragma unroll
    for (int m = 0; m < 4; ++m) { o[m][0] = (f32x4){0.f,0.f,0.f,0.f}; o[m][1] = (f32x4){0.f,0.f,0.f,0.f}; }

#pragma unroll
    for (int ph = 0; ph < 2; ++ph) {
      if (ph == 1) asm volatile("s_waitcnt lgkmcnt(0)" ::: "memory");  // WAR: ph0 reads done
#pragma unroll
      for (int n2 = 0; n2 < 2; ++n2) {
        int n  = ph * 2 + n2;
        int kh = n2 * 16 + l16;                  // key within half [0,32)
        int kb = (kh & 7) << 1;
#pragma unroll
        for (int m = 0; m < 4; ++m)
#pragma unroll
          for (int r = 0; r < 4; ++r) {
            int row = m * 16 + quad * 4 + r;
            *(u16*)(sP + row * 64 + ((((kh >> 3) ^ (row & 3)) << 4) | kb)) = f2bf(s[m][n][r]);
          }
      }
      asm volatile("s_waitcnt lgkmcnt(0)" ::: "memory");               // RAW: writes visible
      bf16x8 vf[2], pa[4];
#pragma unroll
      for (int n = 0; n < 2; ++n) {
        int cc = cb + n * 16 + l16;
        vf[n] = *(const bf16x8*)(smem + OFF_VT + cc * 128 + (((ph * 4 + quad) ^ (cc & 7)) << 4));
      }
#pragma unroll
      for (int m = 0; m < 4; ++m) {
        int row = m * 16 + l16;
        pa[m] = *(const bf16x8*)(sP + row * 64 + ((quad ^ (row & 3)) << 4));
      }
#pragma unroll
      for (int m = 0; m < 4; ++m)
#pragma unroll
        for (int n = 0; n < 2; ++n)
          o[m][n] = MFMA16(pa[m], vf[n], o[m][n], 0, 0, 0);
    }

    // output: roll-back is +3 (NOT +4); channel c = eidx*8 + head
#pragma unroll
    for (int m = 0; m < 4; ++m)
#pragma unroll
      for (int r = 0; r < 4; ++r) {
        int row = m * 16 + quad * 4 + r;
        if (row < 49) {
          int i = row / 7, j = row % 7;
          int dh = u * 7 + i + 3; if (dh >= 56) dh -= 56;
          int dw = v * 7 + j + 3; if (dw >= 56) dw -= 56;
          float inv = 1.f / rsum[m][r];
          float* op = out + ((b * 56 + dh) * 56 + dw) * 256 + hh;
          op[l16 * 8]         = o[m][0][r] * inv;
          op[(16 + l16) * 8]  = o[m][1][r] * inv;
        }
      }
  }
}

extern "C" void kernel_launch(void* const* d_in, const int* in_sizes, int n_in,
                              void* d_out, int out_size, void* d_ws, size_t ws_size,
                              hipStream_t stream) {
  const float* x   = (const float*)d_in[0];
  const float* w1  = (const float*)d_in[1];
  const float* b1  = (const float*)d_in[2];
  const float* pos = (const float*)d_in[3];
  const size_t need = (size_t)768 * 256 * 2 + 768 * 4;
  if (ws_size < need) return;                    // visible failure instead of corruption
  u16*   wT = (u16*)d_ws;
  float* bp = (float*)((char*)d_ws + 768 * 256 * 2);
  prep_w<<<192, 256, 0, stream>>>(w1, b1, wT, bp);
  swin_fused<<<2048, 512, 0, stream>>>(x, wT, bp, pos, (float*)d_out);
}